// Round 1
// baseline (73.963 us; speedup 1.0000x reference)
//
#include <hip/hip_runtime.h>

typedef __attribute__((ext_vector_type(8))) short short8;
typedef __attribute__((ext_vector_type(4))) float f32x4;

#define MFMA(a, b, c) __builtin_amdgcn_mfma_f32_16x16x32_bf16(a, b, c, 0, 0, 0)

__device__ __forceinline__ unsigned int f2bf(float f) {
    unsigned int u = __float_as_uint(f);
    return (u + 0x7fffu + ((u >> 16) & 1u)) >> 16;  // RNE f32->bf16
}

// ---------------- prep: weights -> MFMA A-fragment order (bf16), BN folded ----------------
// w1a: [16 mtiles][64 lanes][8]  A[o][k], o=mt*16+(lane&15), k=(lane>>4)*8+e, k<27 from w1*inv
// w2a: [kt*8+mt][64][8]          A[o][k], o=mt*16+(lane&15), k=kt*32+(lane>>4)*8+e
// w3a: [kt][64][8]               A[o][k], o=lane&15,         k=kt*32+(lane>>4)*8+e
__global__ void prep_kernel(const float* __restrict__ w1, const float* __restrict__ b1,
                            const float* __restrict__ gamma, const float* __restrict__ beta,
                            const float* __restrict__ mean, const float* __restrict__ var,
                            const float* __restrict__ w2, const float* __restrict__ w3,
                            unsigned short* __restrict__ w1a, unsigned short* __restrict__ w2a,
                            unsigned short* __restrict__ w3a, float* __restrict__ bias1) {
    int idx = blockIdx.x * 256 + threadIdx.x;
    if (idx < 256) {
        float inv = gamma[idx] * rsqrtf(var[idx] + 1e-5f);
        bias1[idx] = b1[idx] * inv + beta[idx] - mean[idx] * inv;
    }
    if (idx < 8192) {
        int mt = idx >> 9, r = idx & 511, lane = r >> 3, e = r & 7;
        int o = mt * 16 + (lane & 15);
        int k = ((lane >> 4) << 3) + e;
        float inv = gamma[o] * rsqrtf(var[o] + 1e-5f);
        float v = (k < 27) ? w1[o * 27 + k] * inv : 0.0f;
        w1a[idx] = (unsigned short)f2bf(v);
    }
    if (idx < 32768) {
        int tile = idx >> 9, r = idx & 511, lane = r >> 3, e = r & 7;
        int kt = tile >> 3, mt = tile & 7;
        int o = mt * 16 + (lane & 15);
        int k = kt * 32 + ((lane >> 4) << 3) + e;
        w2a[idx] = (unsigned short)f2bf(w2[o * 256 + k]);
    }
    if (idx < 2048) {
        int kt = idx >> 9, r = idx & 511, lane = r >> 3, e = r & 7;
        int o = lane & 15;
        int k = kt * 32 + ((lane >> 4) << 3) + e;
        w3a[idx] = (unsigned short)f2bf(w3[o * 128 + k]);
    }
}

// ---------------- main: one 16x16 block (even block-col only) per workgroup ----------------
// grid = 4 * 32 * 16 = 2048 blocks of 256 threads (4 waves)
__global__ __launch_bounds__(256, 2)
void fused_block_kernel(const float* __restrict__ x,
                        const unsigned short* __restrict__ w1a,
                        const unsigned short* __restrict__ w2a,
                        const unsigned short* __restrict__ w3a,
                        const float* __restrict__ bias1, const float* __restrict__ b2,
                        const float* __restrict__ b3, float* __restrict__ out) {
    __shared__ unsigned short A1[256 * 40];   // im2col [pixel][k(27->32) pad40]
    __shared__ unsigned short A2[64 * 264];   // feat tile [pixel][256 pad264]
    __shared__ unsigned short A3[64 * 136];   // h tile    [pixel][128 pad136]
    __shared__ float patch[3 * 18 * 18];
    __shared__ float poolW[4][16];
    __shared__ float poolF[16];

    int tid = threadIdx.x;
    int bid = blockIdx.x;
    int b  = bid >> 9;
    int br = (bid >> 4) & 31;
    int j  = bid & 15;          // block col = 2*j (only even block-cols feed the output)
    int r0 = br * 16;
    int c0 = j * 32;
    int lane = tid & 63;
    int w = tid >> 6;
    int lrow = (lane >> 4) << 2;   // C-frag row base
    int lk8  = (lane >> 4) << 3;   // A/B-frag k base

    // stage x patch (3ch x 18x18, SAME zero-pad)
    for (int i = tid; i < 972; i += 256) {
        int ch = i / 324, rr = (i % 324) / 18, cc = i % 18;
        int gr = r0 + rr - 1, gc = c0 + cc - 1;
        float v = 0.0f;
        if ((unsigned)gr < 512u && (unsigned)gc < 512u)
            v = x[((b * 3 + ch) * 512 + gr) * 512 + gc];
        patch[i] = v;
    }
    __syncthreads();

    // im2col -> A1 (each thread owns one pixel)
    {
        int p = tid, pr = p >> 4, pc = p & 15;
        unsigned int vals[32];
        #pragma unroll
        for (int k = 0; k < 27; k++) {
            int ch = k / 9, dy = (k % 9) / 3, dx = k % 3;
            vals[k] = f2bf(patch[ch * 324 + (pr + dy) * 18 + (pc + dx)]);
        }
        #pragma unroll
        for (int k = 27; k < 32; k++) vals[k] = 0;
        #pragma unroll
        for (int q = 0; q < 4; q++) {
            uint4 u;
            u.x = vals[q*8+0] | (vals[q*8+1] << 16);
            u.y = vals[q*8+2] | (vals[q*8+3] << 16);
            u.z = vals[q*8+4] | (vals[q*8+5] << 16);
            u.w = vals[q*8+6] | (vals[q*8+7] << 16);
            *(uint4*)&A1[p * 40 + q * 8] = u;
        }
    }

    // hoist W1/W3 fragments + biases (invariant across tiles)
    short8 w1f[4], w3f[4];
    #pragma unroll
    for (int mi = 0; mi < 4; mi++)
        w1f[mi] = *(const short8*)&w1a[(w * 4 + mi) * 512 + lane * 8];
    #pragma unroll
    for (int kt = 0; kt < 4; kt++)
        w3f[kt] = *(const short8*)&w3a[kt * 512 + lane * 8];
    float b1r[4][4], b2r[2][4];
    #pragma unroll
    for (int mi = 0; mi < 4; mi++)
        #pragma unroll
        for (int i = 0; i < 4; i++)
            b1r[mi][i] = bias1[w * 64 + mi * 16 + lrow + i];
    #pragma unroll
    for (int mi = 0; mi < 2; mi++)
        #pragma unroll
        for (int i = 0; i < 4; i++)
            b2r[mi][i] = b2[w * 32 + mi * 16 + lrow + i];

    f32x4 accP = {0.f, 0.f, 0.f, 0.f};
    __syncthreads();

    for (int t = 0; t < 4; t++) {
        int pt = t * 64;

        // ---- GEMM1: featT[256 och][64 px] = W1(A) x im2col(B), K=32 ----
        short8 bfr[4];
        #pragma unroll
        for (int nj = 0; nj < 4; nj++)
            bfr[nj] = *(const short8*)&A1[(pt + nj * 16 + (lane & 15)) * 40 + lk8];
        f32x4 acc1[4][4];
        #pragma unroll
        for (int mi = 0; mi < 4; mi++)
            #pragma unroll
            for (int nj = 0; nj < 4; nj++) {
                f32x4 z = {0.f, 0.f, 0.f, 0.f};
                acc1[mi][nj] = MFMA(w1f[mi], bfr[nj], z);
            }
        // epilogue: +bias, relu, ->bf16, store A2[pixel][och]
        #pragma unroll
        for (int mi = 0; mi < 4; mi++)
            #pragma unroll
            for (int nj = 0; nj < 4; nj++) {
                int lp = nj * 16 + (lane & 15);
                int oc = w * 64 + mi * 16 + lrow;
                float v0 = fmaxf(acc1[mi][nj][0] + b1r[mi][0], 0.f);
                float v1 = fmaxf(acc1[mi][nj][1] + b1r[mi][1], 0.f);
                float v2 = fmaxf(acc1[mi][nj][2] + b1r[mi][2], 0.f);
                float v3 = fmaxf(acc1[mi][nj][3] + b1r[mi][3], 0.f);
                uint2 pk;
                pk.x = f2bf(v0) | (f2bf(v1) << 16);
                pk.y = f2bf(v2) | (f2bf(v3) << 16);
                *(uint2*)&A2[lp * 264 + oc] = pk;
            }
        __syncthreads();

        // ---- GEMM2: hT[128][64 px] = W2(A) x feat(B), K=256 ----
        f32x4 acc2[2][4];
        #pragma unroll
        for (int mi = 0; mi < 2; mi++)
            #pragma unroll
            for (int nj = 0; nj < 4; nj++)
                acc2[mi][nj] = (f32x4){0.f, 0.f, 0.f, 0.f};
        #pragma unroll
        for (int kt = 0; kt < 8; kt++) {
            short8 w2f[2];
            #pragma unroll
            for (int mi = 0; mi < 2; mi++)
                w2f[mi] = *(const short8*)&w2a[(kt * 8 + w * 2 + mi) * 512 + lane * 8];
            short8 b2f[4];
            #pragma unroll
            for (int nj = 0; nj < 4; nj++)
                b2f[nj] = *(const short8*)&A2[(nj * 16 + (lane & 15)) * 264 + kt * 32 + lk8];
            #pragma unroll
            for (int mi = 0; mi < 2; mi++)
                #pragma unroll
                for (int nj = 0; nj < 4; nj++)
                    acc2[mi][nj] = MFMA(w2f[mi], b2f[nj], acc2[mi][nj]);
        }
        #pragma unroll
        for (int mi = 0; mi < 2; mi++)
            #pragma unroll
            for (int nj = 0; nj < 4; nj++) {
                int lp = nj * 16 + (lane & 15);
                int oc = w * 32 + mi * 16 + lrow;
                float v0 = fmaxf(acc2[mi][nj][0] + b2r[mi][0], 0.f);
                float v1 = fmaxf(acc2[mi][nj][1] + b2r[mi][1], 0.f);
                float v2 = fmaxf(acc2[mi][nj][2] + b2r[mi][2], 0.f);
                float v3 = fmaxf(acc2[mi][nj][3] + b2r[mi][3], 0.f);
                uint2 pk;
                pk.x = f2bf(v0) | (f2bf(v1) << 16);
                pk.y = f2bf(v2) | (f2bf(v3) << 16);
                *(uint2*)&A3[lp * 136 + oc] = pk;
            }
        __syncthreads();

        // ---- GEMM3: logitsT[16][16 px per wave], K=128, accumulate across tiles ----
        #pragma unroll
        for (int kt = 0; kt < 4; kt++) {
            short8 b3f = *(const short8*)&A3[(w * 16 + (lane & 15)) * 136 + kt * 32 + lk8];
            accP = MFMA(w3f[kt], b3f, accP);
        }
        __syncthreads();
    }

    // reduce accP over the 16 pixel-columns within each 16-lane group
    float v0 = accP[0], v1 = accP[1], v2 = accP[2], v3 = accP[3];
    #pragma unroll
    for (int off = 1; off < 16; off <<= 1) {
        v0 += __shfl_xor(v0, off);
        v1 += __shfl_xor(v1, off);
        v2 += __shfl_xor(v2, off);
        v3 += __shfl_xor(v3, off);
    }
    if ((lane & 15) == 0) {
        poolW[w][lrow + 0] = v0;
        poolW[w][lrow + 1] = v1;
        poolW[w][lrow + 2] = v2;
        poolW[w][lrow + 3] = v3;
    }
    __syncthreads();
    if (tid < 16) {
        float s = poolW[0][tid] + poolW[1][tid] + poolW[2][tid] + poolW[3][tid];
        poolF[tid] = s * (1.0f / 256.0f) + b3[tid];
    }
    __syncthreads();

    // broadcast store: out[b][c][h=br*16+j][:] = poolF[c]
    int h = r0 + j;
    int c = tid >> 4;
    float pv = poolF[c];
    float4 vv = {pv, pv, pv, pv};
    float4* rowp = (float4*)(out + (size_t)(((b * 16 + c) * 512 + h)) * 512);
    int base = tid & 15;
    #pragma unroll
    for (int ii = 0; ii < 8; ii++)
        rowp[ii * 16 + base] = vv;
}

extern "C" void kernel_launch(void* const* d_in, const int* in_sizes, int n_in,
                              void* d_out, int out_size, void* d_ws, size_t ws_size,
                              hipStream_t stream) {
    const float* x     = (const float*)d_in[0];
    const float* w1    = (const float*)d_in[1];
    const float* b1    = (const float*)d_in[2];
    const float* gamma = (const float*)d_in[3];
    const float* beta  = (const float*)d_in[4];
    const float* mean  = (const float*)d_in[5];
    const float* var   = (const float*)d_in[6];
    const float* w2    = (const float*)d_in[7];
    const float* b2    = (const float*)d_in[8];
    const float* w3    = (const float*)d_in[9];
    const float* b3    = (const float*)d_in[10];
    float* out = (float*)d_out;

    unsigned short* w1a = (unsigned short*)d_ws;        // 8192 bf16
    unsigned short* w2a = w1a + 8192;                   // 32768 bf16
    unsigned short* w3a = w2a + 32768;                  // 2048 bf16
    float* bias1 = (float*)(w3a + 2048);                // 256 f32

    prep_kernel<<<128, 256, 0, stream>>>(w1, b1, gamma, beta, mean, var, w2, w3,
                                         w1a, w2a, w3a, bias1);
    fused_block_kernel<<<2048, 256, 0, stream>>>(x, w1a, w2a, w3a, bias1, b2, b3, out);
}